// Round 6
// baseline (2255.419 us; speedup 1.0000x reference)
//
#include <hip/hip_runtime.h>
#include <hip/hip_fp16.h>
#include <math.h>

#define NN 50000
#define NE 640000
#define F  32
#define KCH 9
#define CUT 5.0f

#define C13 (1.0f/3.0f)
#define C23 (2.0f/3.0f)
#define C15 0.2f
#define C25 0.4f
#define C17 (1.0f/7.0f)
#define C27 (2.0f/7.0f)
#define IS3 0.5773502691896258f
#define S35 0.3464101615137755f
#define S37 0.2474358296526968f
#define S3  1.7320508075688772f

// xh layout: per node 32 f-rows of 12 halves (9 used) = 768 B/node, 24 B/lane
#define XH_NODE_B 768

union U2H { unsigned int u; __half2 h; };

__device__ __forceinline__ unsigned int pack2(float a, float b) {
    U2H c; c.h = __floats2half2_rn(a, b); return c.u;
}
__device__ __forceinline__ float2 unpack2(unsigned int u) {
    U2H c; c.u = u; return __half22float2(c.h);
}

__global__ __launch_bounds__(256) void init_x(const float* __restrict__ embed,
                                              const int* __restrict__ Z,
                                              float* __restrict__ x,
                                              char* __restrict__ xh) {
    int idx = blockIdx.x * 256 + threadIdx.x;   // n*32 + f
    int n = idx >> 5, f = idx & 31;
    float v = embed[Z[n] * F + f];
    float* xp = x + (size_t)n * KCH * F + f;
    xp[0] = v;
    #pragma unroll
    for (int a = 1; a < KCH; ++a) xp[a * F] = 0.f;
    char* bp = xh + (size_t)n * XH_NODE_B + f * 24;
    uint2 u0; u0.x = pack2(v, 0.f); u0.y = 0u;
    uint2 zz; zz.x = 0u; zz.y = 0u;
    *(uint2*)bp = u0;
    *(uint2*)(bp + 8) = zz;
    *(uint2*)(bp + 16) = zz;
}

__global__ __launch_bounds__(256) void hist_kernel(const int* __restrict__ idx_i,
                                                   const int* __restrict__ idx_j,
                                                   const float* __restrict__ dr,
                                                   int* __restrict__ cnt) {
    int e = blockIdx.x * 256 + threadIdx.x;
    if (e >= NE) return;
    int ni = idx_i[e], nj = idx_j[e];
    float dx = dr[3 * e + 0], dy = dr[3 * e + 1], dz = dr[3 * e + 2];
    float r2 = fmaf(dx, dx, fmaf(dy, dy, dz * dz));
    if (ni != nj && r2 < CUT * CUT) atomicAdd(&cnt[ni], 1);
}

#define SCAN_T 1024
#define SCAN_C ((NN + SCAN_T - 1) / SCAN_T)

__global__ __launch_bounds__(SCAN_T) void scan_kernel(const int* __restrict__ cnt,
                                                      int* __restrict__ offs,
                                                      int* __restrict__ head) {
    __shared__ int ps[SCAN_T];
    int t = threadIdx.x;
    int b = t * SCAN_C;
    int e = min(b + SCAN_C, NN);
    int s = 0;
    for (int i = b; i < e; ++i) s += cnt[i];
    ps[t] = s;
    __syncthreads();
    for (int off = 1; off < SCAN_T; off <<= 1) {
        int v = (t >= off) ? ps[t - off] : 0;
        __syncthreads();
        ps[t] += v;
        __syncthreads();
    }
    int run = (t == 0) ? 0 : ps[t - 1];
    for (int i = b; i < e; ++i) { int c = cnt[i]; offs[i] = run; head[i] = run; run += c; }
    if (t == SCAN_T - 1) offs[NN] = ps[SCAN_T - 1];
}

// edge record: 3 uint2 (24 B): {u_xy, u_z_pad}, {rc01, rc23}, {rc45, rc67}; nj in njarr
__global__ __launch_bounds__(256) void fill_kernel(const int* __restrict__ idx_i,
                                                   const int* __restrict__ idx_j,
                                                   const float* __restrict__ dr,
                                                   int* __restrict__ head,
                                                   uint2* __restrict__ erec,
                                                   int* __restrict__ njarr) {
    int e = blockIdx.x * 256 + threadIdx.x;
    if (e >= NE) return;
    int ni = idx_i[e], nj = idx_j[e];
    float dx = dr[3 * e + 0], dy = dr[3 * e + 1], dz = dr[3 * e + 2];
    float r2 = fmaf(dx, dx, fmaf(dy, dy, dz * dz));
    if (!(ni != nj && r2 < CUT * CUT)) return;

    float r = sqrtf(r2);
    float inv = 1.0f / fmaxf(r, 1e-9f);
    float ux = dx * inv, uy = dy * inv, uz = dz * inv;

    float cut = expf(-r2 / fmaxf(CUT * CUT - r2, 1e-12f));
    float ur = r / (1.0f + r), vr = 1.0f - ur;
    float up2 = ur*ur, up3 = up2*ur, up4 = up3*ur, up5 = up4*ur, up6 = up5*ur, up7 = up6*ur;
    float vp2 = vr*vr, vp3 = vp2*vr, vp4 = vp3*vr, vp5 = vp4*vr, vp6 = vp5*vr, vp7 = vp6*vr;

    float rc0 = cut * vp7;
    float rc1 = cut * 7.f  * ur  * vp6;
    float rc2 = cut * 21.f * up2 * vp5;
    float rc3 = cut * 35.f * up3 * vp4;
    float rc4 = cut * 35.f * up4 * vp3;
    float rc5 = cut * 21.f * up5 * vp2;
    float rc6 = cut * 7.f  * up6 * vr;
    float rc7 = cut * up7;

    int p = atomicAdd(&head[ni], 1);
    uint2 e0, e1, e2;
    e0.x = pack2(ux, uy); e0.y = pack2(uz, 0.f);
    e1.x = pack2(rc0, rc1); e1.y = pack2(rc2, rc3);
    e2.x = pack2(rc4, rc5); e2.y = pack2(rc6, rc7);
    erec[(size_t)3 * p + 0] = e0;
    erec[(size_t)3 * p + 1] = e1;
    erec[(size_t)3 * p + 2] = e2;
    njarr[p] = nj;
}

// one wave64 per node; half-wave = one edge stream, lane&31 = feature.
// xh prefetched depth-2 via separate nj stream; rec depth-1; branch-free clamps.
// __launch_bounds__(256,8): force VGPR<=64 so 8 waves/SIMD are resident.
template<int LAST>
__global__ __launch_bounds__(256, 8) void gather_kernel(const uint2* __restrict__ erec,
                                                        const int* __restrict__ njarr,
                                                        const char* __restrict__ xh,
                                                        const float* __restrict__ rw_iter,
                                                        const int* __restrict__ offs,
                                                        float* __restrict__ m) {
    const int NWAVES = 2048 * 4;
    int lane = threadIdx.x & 63;
    int wid  = threadIdx.x >> 6;
    int half = lane >> 5;
    int f    = lane & 31;
    int gw   = blockIdx.x * 4 + wid;

    float rwv[24];
    #pragma unroll
    for (int lb = 0; lb < 24; ++lb) rwv[lb] = rw_iter[lb * F + f];
    if (LAST) {
        #pragma unroll
        for (int lb = 8; lb < 16; ++lb) rwv[lb] *= C13;
        #pragma unroll
        for (int lb = 16; lb < 24; ++lb) rwv[lb] *= C15;
    }

    constexpr int NACC = LAST ? 1 : KCH;

    for (int n = gw; n < NN; n += NWAVES) {
        int start = offs[n], end = offs[n + 1];

        float acc[NACC];
        #pragma unroll
        for (int a = 0; a < NACC; ++a) acc[a] = 0.f;

        int t = start + half;
        uint2 e0_c = {}, e1_c = {}, e2_c = {};
        uint2 xa_c = {}, xb_c = {};
        unsigned int xc_c = 0;
        int nj_n = 0;

        if (t < end) {
            e0_c = erec[(size_t)3 * t + 0];
            e1_c = erec[(size_t)3 * t + 1];
            e2_c = erec[(size_t)3 * t + 2];
            int nj0 = njarr[t];
            const char* bp = xh + (size_t)nj0 * XH_NODE_B + f * 24;
            xa_c = *(const uint2*)bp;
            xb_c = *(const uint2*)(bp + 8);
            xc_c = *(const unsigned int*)(bp + 16);
            int t2 = (t + 2 < end) ? t + 2 : t;
            nj_n = njarr[t2];
        }

        while (t < end) {
            int tn = t + 2;
            int tnc = (tn < end) ? tn : t;           // clamped, branch-free
            int tfc = (tn + 2 < end) ? tn + 2 : tnc;

            uint2 e0_n = erec[(size_t)3 * tnc + 0];
            uint2 e1_n = erec[(size_t)3 * tnc + 1];
            uint2 e2_n = erec[(size_t)3 * tnc + 2];
            int nj_f = njarr[tfc];
            const char* bp = xh + (size_t)nj_n * XH_NODE_B + f * 24;
            uint2 xa_n = *(const uint2*)bp;
            uint2 xb_n = *(const uint2*)(bp + 8);
            unsigned int xc_n = *(const unsigned int*)(bp + 16);

            // ---- unpack current edge ----
            float2 uxy = unpack2(e0_c.x);
            float ux = uxy.x, uy = uxy.y;
            float uz = unpack2(e0_c.y).x;
            float2 rcA = unpack2(e1_c.x);   // rc0, rc1
            float2 rcB = unpack2(e1_c.y);   // rc2, rc3
            float2 rcC = unpack2(e2_c.x);   // rc4, rc5
            float2 rcD = unpack2(e2_c.y);   // rc6, rc7

            float xe[9];
            {
                float2 p;
                p = unpack2(xa_c.x); xe[0] = p.x; xe[1] = p.y;
                p = unpack2(xa_c.y); xe[2] = p.x; xe[3] = p.y;
                p = unpack2(xb_c.x); xe[4] = p.x; xe[5] = p.y;
                p = unpack2(xb_c.y); xe[6] = p.x; xe[7] = p.y;
                p = unpack2(xc_c);   xe[8] = p.x;
            }

            float g0, g1, g2;
            g0 = rcA.x * rwv[0];
            g0 = fmaf(rcA.y, rwv[1], g0); g0 = fmaf(rcB.x, rwv[2], g0); g0 = fmaf(rcB.y, rwv[3], g0);
            g0 = fmaf(rcC.x, rwv[4], g0); g0 = fmaf(rcC.y, rwv[5], g0); g0 = fmaf(rcD.x, rwv[6], g0);
            g0 = fmaf(rcD.y, rwv[7], g0);
            g1 = rcA.x * rwv[8];
            g1 = fmaf(rcA.y, rwv[9],  g1); g1 = fmaf(rcB.x, rwv[10], g1); g1 = fmaf(rcB.y, rwv[11], g1);
            g1 = fmaf(rcC.x, rwv[12], g1); g1 = fmaf(rcC.y, rwv[13], g1); g1 = fmaf(rcD.x, rwv[14], g1);
            g1 = fmaf(rcD.y, rwv[15], g1);
            g2 = rcA.x * rwv[16];
            g2 = fmaf(rcA.y, rwv[17], g2); g2 = fmaf(rcB.x, rwv[18], g2); g2 = fmaf(rcB.y, rwv[19], g2);
            g2 = fmaf(rcC.x, rwv[20], g2); g2 = fmaf(rcC.y, rwv[21], g2); g2 = fmaf(rcD.x, rwv[22], g2);
            g2 = fmaf(rcD.y, rwv[23], g2);

            if (LAST) {
                float dot1 = uy * xe[1];
                dot1 = fmaf(uz, xe[2], dot1);
                dot1 = fmaf(ux, xe[3], dot1);
                float Y4 = S3 * ux * uy, Y5 = S3 * uy * uz, Y7 = S3 * ux * uz;
                float Y6 = fmaf(1.5f * uz, uz, -0.5f);
                float Y8 = 0.5f * S3 * (ux * ux - uy * uy);
                float dot2 = Y4 * xe[4];
                dot2 = fmaf(Y5, xe[5], dot2);
                dot2 = fmaf(Y6, xe[6], dot2);
                dot2 = fmaf(Y7, xe[7], dot2);
                dot2 = fmaf(Y8, xe[8], dot2);
                acc[0] = fmaf(g0, xe[0], acc[0]);
                acc[0] = fmaf(g1, dot1, acc[0]);
                acc[0] = fmaf(g2, dot2, acc[0]);
            } else {
                float s2 = S3 * g2;
                float w[9];
                w[0] = g0;
                w[1] = uy * g1; w[2] = uz * g1; w[3] = ux * g1;
                w[4] = s2 * ux * uy;
                w[5] = s2 * uy * uz;
                w[6] = fmaf(1.5f * uz, uz, -0.5f) * g2;
                w[7] = s2 * ux * uz;
                w[8] = 0.5f * s2 * (ux * ux - uy * uy);

                float d0 = xe[0]*w[0], d1 = xe[1]*w[1], d2 = xe[2]*w[2], d3 = xe[3]*w[3];
                float d4 = xe[4]*w[4], d5 = xe[5]*w[5], d6 = xe[6]*w[6], d7 = xe[7]*w[7];
                float d8 = xe[8]*w[8];

                acc[0] += d0 + C13 * (d1 + d2 + d3) + C15 * (d4 + d5 + d6 + d7 + d8);
                #define T(a, b) (xe[a] * w[b] + xe[b] * w[a])
                acc[1] += T(0,1) - C15 * T(1,6) - S35 * T(1,8) + S35 * T(2,5) + S35 * T(3,4);
                acc[2] += T(0,2) + S35 * T(1,5) + C25 * T(2,6) + S35 * T(3,7);
                acc[3] += T(0,3) + S35 * T(1,4) + S35 * T(2,7) - C15 * T(3,6) + S35 * T(3,8);
                acc[4] += T(0,4) + IS3 * T(1,3) - C27 * T(4,6) + S37 * T(5,7);
                acc[5] += T(0,5) + IS3 * T(1,2) + S37 * T(4,7) + C17 * T(5,6) - S37 * T(5,8);
                acc[6] += T(0,6) - C13 * d1 + C23 * d2 - C13 * d3
                        - C27 * d4 + C17 * d5 + C27 * d6 + C17 * d7 - C27 * d8;
                acc[7] += T(0,7) + IS3 * T(2,3) + S37 * T(4,5) + C17 * T(6,7) + S37 * T(7,8);
                acc[8] += T(0,8) - IS3 * d1 + IS3 * d3 - S37 * d5 + S37 * d7 - C27 * T(6,8);
                #undef T
            }

            e0_c = e0_n; e1_c = e1_n; e2_c = e2_n;
            xa_c = xa_n; xb_c = xb_n; xc_c = xc_n;
            nj_n = nj_f;
            t = tn;
        }

        #pragma unroll
        for (int a = 0; a < NACC; ++a) acc[a] += __shfl_xor(acc[a], 32);

        if (half == 0) {
            if (LAST) {
                m[(size_t)n * F + f] = acc[0];
            } else {
                float* mp = m + (size_t)n * KCH * F + f;
                #pragma unroll
                for (int a = 0; a < KCH; ++a) mp[a * F] = acc[a];
            }
        }
    }
}

// thread = (node, f). LDS tile for cross-feature mixing; per-lane weight columns.
__global__ __launch_bounds__(256) void node_full(float* __restrict__ x,
                                                 const float* __restrict__ m,
                                                 char* __restrict__ xh,
                                                 const float* __restrict__ w1,
                                                 const float* __restrict__ b1,
                                                 const float* __restrict__ w2,
                                                 const float* __restrict__ b2) {
    __shared__ float tile[8][KCH][F];
    int nl = threadIdx.x >> 5, f = threadIdx.x & 31;
    int n = blockIdx.x * 8 + nl;

    float w1c[F];
    #pragma unroll
    for (int fi = 0; fi < F; ++fi) w1c[fi] = w1[fi * F + f];

    float xk[KCH];
    #pragma unroll
    for (int k = 0; k < KCH; ++k) {
        xk[k] = x[((size_t)n * KCH + k) * F + f];
        tile[nl][k][f] = xk[k] + m[((size_t)n * KCH + k) * F + f];
    }
    __syncthreads();

    float o1[KCH];
    #pragma unroll
    for (int k = 0; k < KCH; ++k) {
        float s = 0.f;
        #pragma unroll
        for (int fi = 0; fi < F; ++fi) s = fmaf(tile[nl][k][fi], w1c[fi], s);
        o1[k] = s;
    }
    o1[0] += b1[f];
    float gate = 1.0f / (1.0f + expf(-o1[0]));
    __syncthreads();
    #pragma unroll
    for (int k = 0; k < KCH; ++k) tile[nl][k][f] = o1[k] * gate;
    __syncthreads();

    float w2c[F];
    #pragma unroll
    for (int fi = 0; fi < F; ++fi) w2c[fi] = w2[fi * F + f];

    float xn[KCH];
    #pragma unroll
    for (int k = 0; k < KCH; ++k) {
        float s = (k == 0) ? b2[f] : 0.f;
        #pragma unroll
        for (int fi = 0; fi < F; ++fi) s = fmaf(tile[nl][k][fi], w2c[fi], s);
        xn[k] = xk[k] + s;
        x[((size_t)n * KCH + k) * F + f] = xn[k];
    }

    char* bp = xh + (size_t)n * XH_NODE_B + f * 24;
    uint2 u0, u1, u2;
    u0.x = pack2(xn[0], xn[1]); u0.y = pack2(xn[2], xn[3]);
    u1.x = pack2(xn[4], xn[5]); u1.y = pack2(xn[6], xn[7]);
    u2.x = pack2(xn[8], 0.f);   u2.y = 0u;
    *(uint2*)bp = u0;
    *(uint2*)(bp + 8) = u1;
    *(uint2*)(bp + 16) = u2;
}

__global__ __launch_bounds__(256) void node_last(const float* __restrict__ x,
                                                 const float* __restrict__ m1,
                                                 const float* __restrict__ w1,
                                                 const float* __restrict__ b1,
                                                 const float* __restrict__ w2,
                                                 const float* __restrict__ b2,
                                                 float* __restrict__ out) {
    __shared__ float tile[8][F];
    int nl = threadIdx.x >> 5, f = threadIdx.x & 31;
    int n = blockIdx.x * 8 + nl;

    float w1c[F];
    #pragma unroll
    for (int fi = 0; fi < F; ++fi) w1c[fi] = w1[fi * F + f];

    float x0 = x[(size_t)n * KCH * F + f];
    tile[nl][f] = x0 + m1[(size_t)n * F + f];
    __syncthreads();
    float s = 0.f;
    #pragma unroll
    for (int fi = 0; fi < F; ++fi) s = fmaf(tile[nl][fi], w1c[fi], s);
    s += b1[f];
    float gate = 1.0f / (1.0f + expf(-s));
    float h2 = s * gate;
    __syncthreads();
    tile[nl][f] = h2;
    __syncthreads();
    float w2c[F];
    #pragma unroll
    for (int fi = 0; fi < F; ++fi) w2c[fi] = w2[fi * F + f];
    float o = b2[f];
    #pragma unroll
    for (int fi = 0; fi < F; ++fi) o = fmaf(tile[nl][fi], w2c[fi], o);
    out[(size_t)n * F + f] = x0 + o;
}

extern "C" void kernel_launch(void* const* d_in, const int* in_sizes, int n_in,
                              void* d_out, int out_size, void* d_ws, size_t ws_size,
                              hipStream_t stream) {
    (void)in_sizes; (void)n_in; (void)out_size; (void)ws_size;
    const float* dr    = (const float*)d_in[0];
    const float* embed = (const float*)d_in[1];
    const float* rad_w = (const float*)d_in[2];
    const float* d1w   = (const float*)d_in[3];
    const float* d1b   = (const float*)d_in[4];
    const float* d2w   = (const float*)d_in[5];
    const float* d2b   = (const float*)d_in[6];
    const int*   Z     = (const int*)d_in[7];
    const int*   nidx  = (const int*)d_in[8];
    const int* idx_i = nidx;
    const int* idx_j = nidx + NE;

    // workspace layout (all 16B-aligned)
    float* x = (float*)d_ws;                                  // NN*9*32 f32
    float* m = x + (size_t)NN * KCH * F;                      // NN*9*32 f32
    char*  xh = (char*)(m + (size_t)NN * KCH * F);            // NN*768 B
    uint2* erec = (uint2*)(xh + (size_t)NN * XH_NODE_B);      // 3*NE uint2
    int* njarr = (int*)(erec + (size_t)3 * NE);               // NE
    int* offs = njarr + NE;                                   // NN+1
    int* head = offs + (NN + 1);                              // NN
    int* cnt  = head + NN;                                    // NN
    float* outp = (float*)d_out;

    hipMemsetAsync(cnt, 0, NN * sizeof(int), stream);
    hist_kernel<<<(NE + 255) / 256, 256, 0, stream>>>(idx_i, idx_j, dr, cnt);
    scan_kernel<<<1, SCAN_T, 0, stream>>>(cnt, offs, head);
    fill_kernel<<<(NE + 255) / 256, 256, 0, stream>>>(idx_i, idx_j, dr, head, erec, njarr);

    init_x<<<NN * F / 256, 256, 0, stream>>>(embed, Z, x, xh);

    for (int i = 0; i < 3; ++i) {
        const float* rwi = rad_w + (size_t)i * 3 * 8 * F;
        const float* w1 = d1w + (size_t)i * F * F;
        const float* b1 = d1b + (size_t)i * F;
        const float* w2 = d2w + (size_t)i * F * F;
        const float* b2 = d2b + (size_t)i * F;
        if (i < 2) {
            gather_kernel<0><<<2048, 256, 0, stream>>>(erec, njarr, xh, rwi, offs, m);
            node_full<<<NN / 8, 256, 0, stream>>>(x, m, xh, w1, b1, w2, b2);
        } else {
            gather_kernel<1><<<2048, 256, 0, stream>>>(erec, njarr, xh, rwi, offs, m);
            node_last<<<NN / 8, 256, 0, stream>>>(x, m, w1, b1, w2, b2, outp);
        }
    }
}

// Round 7
// 694.548 us; speedup vs baseline: 3.2473x; 3.2473x over previous
//
#include <hip/hip_runtime.h>
#include <hip/hip_fp16.h>
#include <math.h>

#define NN 50000
#define NE 640000
#define F  32
#define KCH 9
#define CUT 5.0f

#define C13 (1.0f/3.0f)
#define C23 (2.0f/3.0f)
#define C15 0.2f
#define C25 0.4f
#define C17 (1.0f/7.0f)
#define C27 (2.0f/7.0f)
#define IS3 0.5773502691896258f
#define S35 0.3464101615137755f
#define S37 0.2474358296526968f
#define S3  1.7320508075688772f

// xh layout: per node 32 f-rows of 12 halves (9 used) = 768 B/node, 24 B/lane
#define XH_NODE_B 768

union U2H { unsigned int u; __half2 h; };

__device__ __forceinline__ unsigned int pack2(float a, float b) {
    U2H c; c.h = __floats2half2_rn(a, b); return c.u;
}
__device__ __forceinline__ float2 unpack2(unsigned int u) {
    U2H c; c.u = u; return __half22float2(c.h);
}

__global__ __launch_bounds__(256) void init_x(const float* __restrict__ embed,
                                              const int* __restrict__ Z,
                                              float* __restrict__ x,
                                              char* __restrict__ xh) {
    int idx = blockIdx.x * 256 + threadIdx.x;   // n*32 + f
    int n = idx >> 5, f = idx & 31;
    float v = embed[Z[n] * F + f];
    float* xp = x + (size_t)n * KCH * F + f;
    xp[0] = v;
    #pragma unroll
    for (int a = 1; a < KCH; ++a) xp[a * F] = 0.f;
    char* bp = xh + (size_t)n * XH_NODE_B + f * 24;
    uint2 u0; u0.x = pack2(v, 0.f); u0.y = 0u;
    uint2 zz; zz.x = 0u; zz.y = 0u;
    *(uint2*)bp = u0;
    *(uint2*)(bp + 8) = zz;
    *(uint2*)(bp + 16) = zz;
}

__global__ __launch_bounds__(256) void hist_kernel(const int* __restrict__ idx_i,
                                                   const int* __restrict__ idx_j,
                                                   const float* __restrict__ dr,
                                                   int* __restrict__ cnt) {
    int e = blockIdx.x * 256 + threadIdx.x;
    if (e >= NE) return;
    int ni = idx_i[e], nj = idx_j[e];
    float dx = dr[3 * e + 0], dy = dr[3 * e + 1], dz = dr[3 * e + 2];
    float r2 = fmaf(dx, dx, fmaf(dy, dy, dz * dz));
    if (ni != nj && r2 < CUT * CUT) atomicAdd(&cnt[ni], 1);
}

#define SCAN_T 1024
#define SCAN_C ((NN + SCAN_T - 1) / SCAN_T)

__global__ __launch_bounds__(SCAN_T) void scan_kernel(const int* __restrict__ cnt,
                                                      int* __restrict__ offs,
                                                      int* __restrict__ head) {
    __shared__ int ps[SCAN_T];
    int t = threadIdx.x;
    int b = t * SCAN_C;
    int e = min(b + SCAN_C, NN);
    int s = 0;
    for (int i = b; i < e; ++i) s += cnt[i];
    ps[t] = s;
    __syncthreads();
    for (int off = 1; off < SCAN_T; off <<= 1) {
        int v = (t >= off) ? ps[t - off] : 0;
        __syncthreads();
        ps[t] += v;
        __syncthreads();
    }
    int run = (t == 0) ? 0 : ps[t - 1];
    for (int i = b; i < e; ++i) { int c = cnt[i]; offs[i] = run; head[i] = run; run += c; }
    if (t == SCAN_T - 1) offs[NN] = ps[SCAN_T - 1];
}

// edge record: 3 uint2 (24 B): {u_xy, u_z_pad}, {rc01, rc23}, {rc45, rc67}; nj in njarr
__global__ __launch_bounds__(256) void fill_kernel(const int* __restrict__ idx_i,
                                                   const int* __restrict__ idx_j,
                                                   const float* __restrict__ dr,
                                                   int* __restrict__ head,
                                                   uint2* __restrict__ erec,
                                                   int* __restrict__ njarr) {
    int e = blockIdx.x * 256 + threadIdx.x;
    if (e >= NE) return;
    int ni = idx_i[e], nj = idx_j[e];
    float dx = dr[3 * e + 0], dy = dr[3 * e + 1], dz = dr[3 * e + 2];
    float r2 = fmaf(dx, dx, fmaf(dy, dy, dz * dz));
    if (!(ni != nj && r2 < CUT * CUT)) return;

    float r = sqrtf(r2);
    float inv = 1.0f / fmaxf(r, 1e-9f);
    float ux = dx * inv, uy = dy * inv, uz = dz * inv;

    float cut = expf(-r2 / fmaxf(CUT * CUT - r2, 1e-12f));
    float ur = r / (1.0f + r), vr = 1.0f - ur;
    float up2 = ur*ur, up3 = up2*ur, up4 = up3*ur, up5 = up4*ur, up6 = up5*ur, up7 = up6*ur;
    float vp2 = vr*vr, vp3 = vp2*vr, vp4 = vp3*vr, vp5 = vp4*vr, vp6 = vp5*vr, vp7 = vp6*vr;

    float rc0 = cut * vp7;
    float rc1 = cut * 7.f  * ur  * vp6;
    float rc2 = cut * 21.f * up2 * vp5;
    float rc3 = cut * 35.f * up3 * vp4;
    float rc4 = cut * 35.f * up4 * vp3;
    float rc5 = cut * 21.f * up5 * vp2;
    float rc6 = cut * 7.f  * up6 * vr;
    float rc7 = cut * up7;

    int p = atomicAdd(&head[ni], 1);
    uint2 e0, e1, e2;
    e0.x = pack2(ux, uy); e0.y = pack2(uz, 0.f);
    e1.x = pack2(rc0, rc1); e1.y = pack2(rc2, rc3);
    e2.x = pack2(rc4, rc5); e2.y = pack2(rc6, rc7);
    erec[(size_t)3 * p + 0] = e0;
    erec[(size_t)3 * p + 1] = e1;
    erec[(size_t)3 * p + 2] = e2;
    njarr[p] = nj;
}

// one wave64 per node; half-wave = one edge stream, lane&31 = feature.
// Depth-1 prefetch ONLY on the random xh gather (+ nj stream one step ahead);
// erec read just-in-time (sequential / L2-friendly). Minimal live set -> <=64 VGPR.
template<int LAST>
__global__ __launch_bounds__(256) void gather_kernel(const uint2* __restrict__ erec,
                                                     const int* __restrict__ njarr,
                                                     const char* __restrict__ xh,
                                                     const float* __restrict__ rw_iter,
                                                     const int* __restrict__ offs,
                                                     float* __restrict__ m) {
    const int NWAVES = 2048 * 4;
    int lane = threadIdx.x & 63;
    int wid  = threadIdx.x >> 6;
    int half = lane >> 5;
    int f    = lane & 31;
    int gw   = blockIdx.x * 4 + wid;

    float rwv[24];
    #pragma unroll
    for (int lb = 0; lb < 24; ++lb) rwv[lb] = rw_iter[lb * F + f];
    if (LAST) {
        #pragma unroll
        for (int lb = 8; lb < 16; ++lb) rwv[lb] *= C13;
        #pragma unroll
        for (int lb = 16; lb < 24; ++lb) rwv[lb] *= C15;
    }

    constexpr int NACC = LAST ? 1 : KCH;

    for (int n = gw; n < NN; n += NWAVES) {
        int start = offs[n], end = offs[n + 1];

        float acc[NACC];
        #pragma unroll
        for (int a = 0; a < NACC; ++a) acc[a] = 0.f;

        int t = start + half;
        uint2 xa_c = {}, xb_c = {};
        unsigned int xc_c = 0;
        int nj_n = 0;

        if (t < end) {
            int nj0 = njarr[t];
            const char* bp = xh + (size_t)nj0 * XH_NODE_B + f * 24;
            xa_c = *(const uint2*)bp;
            xb_c = *(const uint2*)(bp + 8);
            xc_c = *(const unsigned int*)(bp + 16);
            int t2 = (t + 2 < end) ? t + 2 : t;
            nj_n = njarr[t2];
        }

        while (t < end) {
            int tn = t + 2;
            int tnc = (tn < end) ? tn : t;           // clamped, branch-free
            int tfc = (tn + 2 < end) ? tn + 2 : tnc;

            // prefetch next edge's xh (random access, long latency)
            const char* bp = xh + (size_t)nj_n * XH_NODE_B + f * 24;
            uint2 xa_n = *(const uint2*)bp;
            uint2 xb_n = *(const uint2*)(bp + 8);
            unsigned int xc_n = *(const unsigned int*)(bp + 16);
            int nj_f = njarr[tfc];

            // just-in-time current edge record (sequential stream)
            uint2 e0 = erec[(size_t)3 * t + 0];
            uint2 e1 = erec[(size_t)3 * t + 1];
            uint2 e2 = erec[(size_t)3 * t + 2];

            // ---- unpack current edge ----
            float2 uxy = unpack2(e0.x);
            float ux = uxy.x, uy = uxy.y;
            float uz = unpack2(e0.y).x;
            float2 rcA = unpack2(e1.x);   // rc0, rc1
            float2 rcB = unpack2(e1.y);   // rc2, rc3
            float2 rcC = unpack2(e2.x);   // rc4, rc5
            float2 rcD = unpack2(e2.y);   // rc6, rc7

            float xe[9];
            {
                float2 p;
                p = unpack2(xa_c.x); xe[0] = p.x; xe[1] = p.y;
                p = unpack2(xa_c.y); xe[2] = p.x; xe[3] = p.y;
                p = unpack2(xb_c.x); xe[4] = p.x; xe[5] = p.y;
                p = unpack2(xb_c.y); xe[6] = p.x; xe[7] = p.y;
                p = unpack2(xc_c);   xe[8] = p.x;
            }

            float g0, g1, g2;
            g0 = rcA.x * rwv[0];
            g0 = fmaf(rcA.y, rwv[1], g0); g0 = fmaf(rcB.x, rwv[2], g0); g0 = fmaf(rcB.y, rwv[3], g0);
            g0 = fmaf(rcC.x, rwv[4], g0); g0 = fmaf(rcC.y, rwv[5], g0); g0 = fmaf(rcD.x, rwv[6], g0);
            g0 = fmaf(rcD.y, rwv[7], g0);
            g1 = rcA.x * rwv[8];
            g1 = fmaf(rcA.y, rwv[9],  g1); g1 = fmaf(rcB.x, rwv[10], g1); g1 = fmaf(rcB.y, rwv[11], g1);
            g1 = fmaf(rcC.x, rwv[12], g1); g1 = fmaf(rcC.y, rwv[13], g1); g1 = fmaf(rcD.x, rwv[14], g1);
            g1 = fmaf(rcD.y, rwv[15], g1);
            g2 = rcA.x * rwv[16];
            g2 = fmaf(rcA.y, rwv[17], g2); g2 = fmaf(rcB.x, rwv[18], g2); g2 = fmaf(rcB.y, rwv[19], g2);
            g2 = fmaf(rcC.x, rwv[20], g2); g2 = fmaf(rcC.y, rwv[21], g2); g2 = fmaf(rcD.x, rwv[22], g2);
            g2 = fmaf(rcD.y, rwv[23], g2);

            if (LAST) {
                float dot1 = uy * xe[1];
                dot1 = fmaf(uz, xe[2], dot1);
                dot1 = fmaf(ux, xe[3], dot1);
                float Y4 = S3 * ux * uy, Y5 = S3 * uy * uz, Y7 = S3 * ux * uz;
                float Y6 = fmaf(1.5f * uz, uz, -0.5f);
                float Y8 = 0.5f * S3 * (ux * ux - uy * uy);
                float dot2 = Y4 * xe[4];
                dot2 = fmaf(Y5, xe[5], dot2);
                dot2 = fmaf(Y6, xe[6], dot2);
                dot2 = fmaf(Y7, xe[7], dot2);
                dot2 = fmaf(Y8, xe[8], dot2);
                acc[0] = fmaf(g0, xe[0], acc[0]);
                acc[0] = fmaf(g1, dot1, acc[0]);
                acc[0] = fmaf(g2, dot2, acc[0]);
            } else {
                float s2 = S3 * g2;
                float w[9];
                w[0] = g0;
                w[1] = uy * g1; w[2] = uz * g1; w[3] = ux * g1;
                w[4] = s2 * ux * uy;
                w[5] = s2 * uy * uz;
                w[6] = fmaf(1.5f * uz, uz, -0.5f) * g2;
                w[7] = s2 * ux * uz;
                w[8] = 0.5f * s2 * (ux * ux - uy * uy);

                float d0 = xe[0]*w[0], d1 = xe[1]*w[1], d2 = xe[2]*w[2], d3 = xe[3]*w[3];
                float d4 = xe[4]*w[4], d5 = xe[5]*w[5], d6 = xe[6]*w[6], d7 = xe[7]*w[7];
                float d8 = xe[8]*w[8];

                acc[0] += d0 + C13 * (d1 + d2 + d3) + C15 * (d4 + d5 + d6 + d7 + d8);
                #define T(a, b) (xe[a] * w[b] + xe[b] * w[a])
                acc[1] += T(0,1) - C15 * T(1,6) - S35 * T(1,8) + S35 * T(2,5) + S35 * T(3,4);
                acc[2] += T(0,2) + S35 * T(1,5) + C25 * T(2,6) + S35 * T(3,7);
                acc[3] += T(0,3) + S35 * T(1,4) + S35 * T(2,7) - C15 * T(3,6) + S35 * T(3,8);
                acc[4] += T(0,4) + IS3 * T(1,3) - C27 * T(4,6) + S37 * T(5,7);
                acc[5] += T(0,5) + IS3 * T(1,2) + S37 * T(4,7) + C17 * T(5,6) - S37 * T(5,8);
                acc[6] += T(0,6) - C13 * d1 + C23 * d2 - C13 * d3
                        - C27 * d4 + C17 * d5 + C27 * d6 + C17 * d7 - C27 * d8;
                acc[7] += T(0,7) + IS3 * T(2,3) + S37 * T(4,5) + C17 * T(6,7) + S37 * T(7,8);
                acc[8] += T(0,8) - IS3 * d1 + IS3 * d3 - S37 * d5 + S37 * d7 - C27 * T(6,8);
                #undef T
            }

            xa_c = xa_n; xb_c = xb_n; xc_c = xc_n;
            nj_n = nj_f;
            t = tn;
        }

        #pragma unroll
        for (int a = 0; a < NACC; ++a) acc[a] += __shfl_xor(acc[a], 32);

        if (half == 0) {
            if (LAST) {
                m[(size_t)n * F + f] = acc[0];
            } else {
                float* mp = m + (size_t)n * KCH * F + f;
                #pragma unroll
                for (int a = 0; a < KCH; ++a) mp[a * F] = acc[a];
            }
        }
    }
}

// thread = (node, f). LDS tile for cross-feature mixing; per-lane weight columns.
__global__ __launch_bounds__(256) void node_full(float* __restrict__ x,
                                                 const float* __restrict__ m,
                                                 char* __restrict__ xh,
                                                 const float* __restrict__ w1,
                                                 const float* __restrict__ b1,
                                                 const float* __restrict__ w2,
                                                 const float* __restrict__ b2) {
    __shared__ float tile[8][KCH][F];
    int nl = threadIdx.x >> 5, f = threadIdx.x & 31;
    int n = blockIdx.x * 8 + nl;

    float w1c[F];
    #pragma unroll
    for (int fi = 0; fi < F; ++fi) w1c[fi] = w1[fi * F + f];

    float xk[KCH];
    #pragma unroll
    for (int k = 0; k < KCH; ++k) {
        xk[k] = x[((size_t)n * KCH + k) * F + f];
        tile[nl][k][f] = xk[k] + m[((size_t)n * KCH + k) * F + f];
    }
    __syncthreads();

    float o1[KCH];
    #pragma unroll
    for (int k = 0; k < KCH; ++k) {
        float s = 0.f;
        #pragma unroll
        for (int fi = 0; fi < F; ++fi) s = fmaf(tile[nl][k][fi], w1c[fi], s);
        o1[k] = s;
    }
    o1[0] += b1[f];
    float gate = 1.0f / (1.0f + expf(-o1[0]));
    __syncthreads();
    #pragma unroll
    for (int k = 0; k < KCH; ++k) tile[nl][k][f] = o1[k] * gate;
    __syncthreads();

    float w2c[F];
    #pragma unroll
    for (int fi = 0; fi < F; ++fi) w2c[fi] = w2[fi * F + f];

    float xn[KCH];
    #pragma unroll
    for (int k = 0; k < KCH; ++k) {
        float s = (k == 0) ? b2[f] : 0.f;
        #pragma unroll
        for (int fi = 0; fi < F; ++fi) s = fmaf(tile[nl][k][fi], w2c[fi], s);
        xn[k] = xk[k] + s;
        x[((size_t)n * KCH + k) * F + f] = xn[k];
    }

    char* bp = xh + (size_t)n * XH_NODE_B + f * 24;
    uint2 u0, u1, u2;
    u0.x = pack2(xn[0], xn[1]); u0.y = pack2(xn[2], xn[3]);
    u1.x = pack2(xn[4], xn[5]); u1.y = pack2(xn[6], xn[7]);
    u2.x = pack2(xn[8], 0.f);   u2.y = 0u;
    *(uint2*)bp = u0;
    *(uint2*)(bp + 8) = u1;
    *(uint2*)(bp + 16) = u2;
}

__global__ __launch_bounds__(256) void node_last(const float* __restrict__ x,
                                                 const float* __restrict__ m1,
                                                 const float* __restrict__ w1,
                                                 const float* __restrict__ b1,
                                                 const float* __restrict__ w2,
                                                 const float* __restrict__ b2,
                                                 float* __restrict__ out) {
    __shared__ float tile[8][F];
    int nl = threadIdx.x >> 5, f = threadIdx.x & 31;
    int n = blockIdx.x * 8 + nl;

    float w1c[F];
    #pragma unroll
    for (int fi = 0; fi < F; ++fi) w1c[fi] = w1[fi * F + f];

    float x0 = x[(size_t)n * KCH * F + f];
    tile[nl][f] = x0 + m1[(size_t)n * F + f];
    __syncthreads();
    float s = 0.f;
    #pragma unroll
    for (int fi = 0; fi < F; ++fi) s = fmaf(tile[nl][fi], w1c[fi], s);
    s += b1[f];
    float gate = 1.0f / (1.0f + expf(-s));
    float h2 = s * gate;
    __syncthreads();
    tile[nl][f] = h2;
    __syncthreads();
    float w2c[F];
    #pragma unroll
    for (int fi = 0; fi < F; ++fi) w2c[fi] = w2[fi * F + f];
    float o = b2[f];
    #pragma unroll
    for (int fi = 0; fi < F; ++fi) o = fmaf(tile[nl][fi], w2c[fi], o);
    out[(size_t)n * F + f] = x0 + o;
}

extern "C" void kernel_launch(void* const* d_in, const int* in_sizes, int n_in,
                              void* d_out, int out_size, void* d_ws, size_t ws_size,
                              hipStream_t stream) {
    (void)in_sizes; (void)n_in; (void)out_size; (void)ws_size;
    const float* dr    = (const float*)d_in[0];
    const float* embed = (const float*)d_in[1];
    const float* rad_w = (const float*)d_in[2];
    const float* d1w   = (const float*)d_in[3];
    const float* d1b   = (const float*)d_in[4];
    const float* d2w   = (const float*)d_in[5];
    const float* d2b   = (const float*)d_in[6];
    const int*   Z     = (const int*)d_in[7];
    const int*   nidx  = (const int*)d_in[8];
    const int* idx_i = nidx;
    const int* idx_j = nidx + NE;

    // workspace layout (all 16B-aligned)
    float* x = (float*)d_ws;                                  // NN*9*32 f32
    float* m = x + (size_t)NN * KCH * F;                      // NN*9*32 f32
    char*  xh = (char*)(m + (size_t)NN * KCH * F);            // NN*768 B
    uint2* erec = (uint2*)(xh + (size_t)NN * XH_NODE_B);      // 3*NE uint2
    int* njarr = (int*)(erec + (size_t)3 * NE);               // NE
    int* offs = njarr + NE;                                   // NN+1
    int* head = offs + (NN + 1);                              // NN
    int* cnt  = head + NN;                                    // NN
    float* outp = (float*)d_out;

    hipMemsetAsync(cnt, 0, NN * sizeof(int), stream);
    hist_kernel<<<(NE + 255) / 256, 256, 0, stream>>>(idx_i, idx_j, dr, cnt);
    scan_kernel<<<1, SCAN_T, 0, stream>>>(cnt, offs, head);
    fill_kernel<<<(NE + 255) / 256, 256, 0, stream>>>(idx_i, idx_j, dr, head, erec, njarr);

    init_x<<<NN * F / 256, 256, 0, stream>>>(embed, Z, x, xh);

    for (int i = 0; i < 3; ++i) {
        const float* rwi = rad_w + (size_t)i * 3 * 8 * F;
        const float* w1 = d1w + (size_t)i * F * F;
        const float* b1 = d1b + (size_t)i * F;
        const float* w2 = d2w + (size_t)i * F * F;
        const float* b2 = d2b + (size_t)i * F;
        if (i < 2) {
            gather_kernel<0><<<2048, 256, 0, stream>>>(erec, njarr, xh, rwi, offs, m);
            node_full<<<NN / 8, 256, 0, stream>>>(x, m, xh, w1, b1, w2, b2);
        } else {
            gather_kernel<1><<<2048, 256, 0, stream>>>(erec, njarr, xh, rwi, offs, m);
            node_last<<<NN / 8, 256, 0, stream>>>(x, m, w1, b1, w2, b2, outp);
        }
    }
}

// Round 8
// 583.511 us; speedup vs baseline: 3.8653x; 1.1903x over previous
//
#include <hip/hip_runtime.h>
#include <hip/hip_fp16.h>
#include <math.h>

#define NN 50000
#define NE 640000
#define F  32
#define KCH 9
#define CUT 5.0f

#define C13 (1.0f/3.0f)
#define C23 (2.0f/3.0f)
#define C15 0.2f
#define C25 0.4f
#define C17 (1.0f/7.0f)
#define C27 (2.0f/7.0f)
#define IS3 0.5773502691896258f
#define S35 0.3464101615137755f
#define S37 0.2474358296526968f
#define S3  1.7320508075688772f

union U2H { unsigned int u; __half2 h; };

__device__ __forceinline__ unsigned int pack2(float a, float b) {
    U2H c; c.h = __floats2half2_rn(a, b); return c.u;
}
__device__ __forceinline__ float2 unpack2(unsigned int u) {
    U2H c; c.u = u; return __half22float2(c.h);
}

__global__ __launch_bounds__(256) void init_x(const float* __restrict__ embed,
                                              const int* __restrict__ Z,
                                              float* __restrict__ x,
                                              __half* __restrict__ x0h) {
    int idx = blockIdx.x * 256 + threadIdx.x;   // n*32 + f
    int n = idx >> 5, f = idx & 31;
    float v = embed[Z[n] * F + f];
    float* xp = x + (size_t)n * KCH * F + f;
    xp[0] = v;
    #pragma unroll
    for (int a = 1; a < KCH; ++a) xp[a * F] = 0.f;
    x0h[idx] = __float2half_rn(v);
}

__global__ __launch_bounds__(256) void hist_kernel(const int* __restrict__ idx_i,
                                                   const int* __restrict__ idx_j,
                                                   const float* __restrict__ dr,
                                                   int* __restrict__ cnt) {
    int e = blockIdx.x * 256 + threadIdx.x;
    if (e >= NE) return;
    int ni = idx_i[e], nj = idx_j[e];
    float dx = dr[3 * e + 0], dy = dr[3 * e + 1], dz = dr[3 * e + 2];
    float r2 = fmaf(dx, dx, fmaf(dy, dy, dz * dz));
    if (ni != nj && r2 < CUT * CUT) atomicAdd(&cnt[ni], 1);
}

#define SCAN_T 1024
#define SCAN_C ((NN + SCAN_T - 1) / SCAN_T)

__global__ __launch_bounds__(SCAN_T) void scan_kernel(const int* __restrict__ cnt,
                                                      int* __restrict__ offs,
                                                      int* __restrict__ head) {
    __shared__ int ps[SCAN_T];
    int t = threadIdx.x;
    int b = t * SCAN_C;
    int e = min(b + SCAN_C, NN);
    int s = 0;
    for (int i = b; i < e; ++i) s += cnt[i];
    ps[t] = s;
    __syncthreads();
    for (int off = 1; off < SCAN_T; off <<= 1) {
        int v = (t >= off) ? ps[t - off] : 0;
        __syncthreads();
        ps[t] += v;
        __syncthreads();
    }
    int run = (t == 0) ? 0 : ps[t - 1];
    for (int i = b; i < e; ++i) { int c = cnt[i]; offs[i] = run; head[i] = run; run += c; }
    if (t == SCAN_T - 1) offs[NN] = ps[SCAN_T - 1];
}

// edge record 24 B: e0 = {u_xy, uz_half | nj<<16}, e1 = {rc01, rc23}, e2 = {rc45, rc67}
__global__ __launch_bounds__(256) void fill_kernel(const int* __restrict__ idx_i,
                                                   const int* __restrict__ idx_j,
                                                   const float* __restrict__ dr,
                                                   int* __restrict__ head,
                                                   uint2* __restrict__ erec) {
    int e = blockIdx.x * 256 + threadIdx.x;
    if (e >= NE) return;
    int ni = idx_i[e], nj = idx_j[e];
    float dx = dr[3 * e + 0], dy = dr[3 * e + 1], dz = dr[3 * e + 2];
    float r2 = fmaf(dx, dx, fmaf(dy, dy, dz * dz));
    if (!(ni != nj && r2 < CUT * CUT)) return;

    float r = sqrtf(r2);
    float inv = 1.0f / fmaxf(r, 1e-9f);
    float ux = dx * inv, uy = dy * inv, uz = dz * inv;

    float cut = expf(-r2 / fmaxf(CUT * CUT - r2, 1e-12f));
    float ur = r / (1.0f + r), vr = 1.0f - ur;
    float up2 = ur*ur, up3 = up2*ur, up4 = up3*ur, up5 = up4*ur, up6 = up5*ur, up7 = up6*ur;
    float vp2 = vr*vr, vp3 = vp2*vr, vp4 = vp3*vr, vp5 = vp4*vr, vp6 = vp5*vr, vp7 = vp6*vr;

    float rc0 = cut * vp7;
    float rc1 = cut * 7.f  * ur  * vp6;
    float rc2 = cut * 21.f * up2 * vp5;
    float rc3 = cut * 35.f * up3 * vp4;
    float rc4 = cut * 35.f * up4 * vp3;
    float rc5 = cut * 21.f * up5 * vp2;
    float rc6 = cut * 7.f  * up6 * vr;
    float rc7 = cut * up7;

    int p = atomicAdd(&head[ni], 1);
    uint2 e0, e1, e2;
    U2H zh; zh.h = __floats2half2_rn(uz, 0.f);
    e0.x = pack2(ux, uy);
    e0.y = (zh.u & 0xFFFFu) | ((unsigned int)nj << 16);
    e1.x = pack2(rc0, rc1); e1.y = pack2(rc2, rc3);
    e2.x = pack2(rc4, rc5); e2.y = pack2(rc6, rc7);
    erec[(size_t)3 * p + 0] = e0;
    erec[(size_t)3 * p + 1] = e1;
    erec[(size_t)3 * p + 2] = e2;
}

// MODE: 0 = FIRST (x only row0 nonzero -> y[c] = xe0*w[c], reads x0h),
//       1 = MID (full Gaunt, reads xhA/xhB), 2 = LAST (y0 only, reads xhA/xhB)
template<int MODE>
__global__ __launch_bounds__(256) void gather_kernel(const uint2* __restrict__ erec,
                                                     const __half* __restrict__ x0h,
                                                     const uint4* __restrict__ xhA,
                                                     const ushort* __restrict__ xhB,
                                                     const float* __restrict__ rw_iter,
                                                     const int* __restrict__ offs,
                                                     float* __restrict__ m) {
    const int NWAVES = 2048 * 4;
    int lane = threadIdx.x & 63;
    int wid  = threadIdx.x >> 6;
    int half = lane >> 5;
    int f    = lane & 31;
    int gw   = blockIdx.x * 4 + wid;

    float rwv[24];
    #pragma unroll
    for (int lb = 0; lb < 24; ++lb) rwv[lb] = rw_iter[lb * F + f];
    if (MODE == 2) {
        #pragma unroll
        for (int lb = 8; lb < 16; ++lb) rwv[lb] *= C13;
        #pragma unroll
        for (int lb = 16; lb < 24; ++lb) rwv[lb] *= C15;
    }

    constexpr int NACC = (MODE == 2) ? 1 : KCH;

    for (int n = gw; n < NN; n += NWAVES) {
        int start = offs[n], end = offs[n + 1];

        float acc[NACC];
        #pragma unroll
        for (int a = 0; a < NACC; ++a) acc[a] = 0.f;

        int t = start + half;
        uint2 e0_c = {}, e0_n = {};
        uint4 xa_c = {};
        ushort x8_c = 0;

        if (t < end) {
            e0_c = erec[(size_t)3 * t + 0];
            int nj0 = (int)(e0_c.y >> 16);
            if (MODE == 0) {
                x8_c = __half_as_ushort(x0h[nj0 * F + f]);
            } else {
                xa_c = xhA[nj0 * F + f];
                x8_c = xhB[nj0 * F + f];
            }
            int t2 = (t + 2 < end) ? t + 2 : t;
            e0_n = erec[(size_t)3 * t2 + 0];
        }

        while (t < end) {
            int tn = t + 2;
            int tnc = (tn < end) ? tn : t;           // clamped, branch-free
            int tfc = (tn + 2 < end) ? tn + 2 : tnc;

            // prefetch next edge's xe (random access, long latency)
            int njn = (int)(e0_n.y >> 16);
            uint4 xa_n = {};
            ushort x8_n;
            if (MODE == 0) {
                x8_n = __half_as_ushort(x0h[njn * F + f]);
            } else {
                xa_n = xhA[njn * F + f];
                x8_n = xhB[njn * F + f];
            }
            uint2 e0_f = erec[(size_t)3 * tfc + 0];

            // just-in-time current edge record tail (sequential stream)
            uint2 e1 = erec[(size_t)3 * t + 1];
            uint2 e2 = erec[(size_t)3 * t + 2];

            // ---- unpack current edge ----
            float2 uxy = unpack2(e0_c.x);
            float ux = uxy.x, uy = uxy.y;
            float uz = unpack2(e0_c.y).x;     // low half; high half is nj
            float2 rcA = unpack2(e1.x);
            float2 rcB = unpack2(e1.y);
            float2 rcC = unpack2(e2.x);
            float2 rcD = unpack2(e2.y);

            float g0, g1, g2;
            g0 = rcA.x * rwv[0];
            g0 = fmaf(rcA.y, rwv[1], g0); g0 = fmaf(rcB.x, rwv[2], g0); g0 = fmaf(rcB.y, rwv[3], g0);
            g0 = fmaf(rcC.x, rwv[4], g0); g0 = fmaf(rcC.y, rwv[5], g0); g0 = fmaf(rcD.x, rwv[6], g0);
            g0 = fmaf(rcD.y, rwv[7], g0);
            g1 = rcA.x * rwv[8];
            g1 = fmaf(rcA.y, rwv[9],  g1); g1 = fmaf(rcB.x, rwv[10], g1); g1 = fmaf(rcB.y, rwv[11], g1);
            g1 = fmaf(rcC.x, rwv[12], g1); g1 = fmaf(rcC.y, rwv[13], g1); g1 = fmaf(rcD.x, rwv[14], g1);
            g1 = fmaf(rcD.y, rwv[15], g1);
            g2 = rcA.x * rwv[16];
            g2 = fmaf(rcA.y, rwv[17], g2); g2 = fmaf(rcB.x, rwv[18], g2); g2 = fmaf(rcB.y, rwv[19], g2);
            g2 = fmaf(rcC.x, rwv[20], g2); g2 = fmaf(rcC.y, rwv[21], g2); g2 = fmaf(rcD.x, rwv[22], g2);
            g2 = fmaf(rcD.y, rwv[23], g2);

            if (MODE == 0) {
                float xe0 = __half2float(__ushort_as_half(x8_c));
                float s2 = S3 * g2;
                acc[0] = fmaf(xe0, g0, acc[0]);
                acc[1] = fmaf(xe0, uy * g1, acc[1]);
                acc[2] = fmaf(xe0, uz * g1, acc[2]);
                acc[3] = fmaf(xe0, ux * g1, acc[3]);
                acc[4] = fmaf(xe0, s2 * ux * uy, acc[4]);
                acc[5] = fmaf(xe0, s2 * uy * uz, acc[5]);
                acc[6] = fmaf(xe0, fmaf(1.5f * uz, uz, -0.5f) * g2, acc[6]);
                acc[7] = fmaf(xe0, s2 * ux * uz, acc[7]);
                acc[8] = fmaf(xe0, 0.5f * s2 * (ux * ux - uy * uy), acc[8]);
            } else {
                float xe[9];
                {
                    float2 p;
                    p = unpack2(xa_c.x); xe[0] = p.x; xe[1] = p.y;
                    p = unpack2(xa_c.y); xe[2] = p.x; xe[3] = p.y;
                    p = unpack2(xa_c.z); xe[4] = p.x; xe[5] = p.y;
                    p = unpack2(xa_c.w); xe[6] = p.x; xe[7] = p.y;
                    xe[8] = __half2float(__ushort_as_half(x8_c));
                }
                if (MODE == 2) {
                    float dot1 = uy * xe[1];
                    dot1 = fmaf(uz, xe[2], dot1);
                    dot1 = fmaf(ux, xe[3], dot1);
                    float Y4 = S3 * ux * uy, Y5 = S3 * uy * uz, Y7 = S3 * ux * uz;
                    float Y6 = fmaf(1.5f * uz, uz, -0.5f);
                    float Y8 = 0.5f * S3 * (ux * ux - uy * uy);
                    float dot2 = Y4 * xe[4];
                    dot2 = fmaf(Y5, xe[5], dot2);
                    dot2 = fmaf(Y6, xe[6], dot2);
                    dot2 = fmaf(Y7, xe[7], dot2);
                    dot2 = fmaf(Y8, xe[8], dot2);
                    acc[0] = fmaf(g0, xe[0], acc[0]);
                    acc[0] = fmaf(g1, dot1, acc[0]);
                    acc[0] = fmaf(g2, dot2, acc[0]);
                } else {
                    float s2 = S3 * g2;
                    float w[9];
                    w[0] = g0;
                    w[1] = uy * g1; w[2] = uz * g1; w[3] = ux * g1;
                    w[4] = s2 * ux * uy;
                    w[5] = s2 * uy * uz;
                    w[6] = fmaf(1.5f * uz, uz, -0.5f) * g2;
                    w[7] = s2 * ux * uz;
                    w[8] = 0.5f * s2 * (ux * ux - uy * uy);

                    float d0 = xe[0]*w[0], d1 = xe[1]*w[1], d2 = xe[2]*w[2], d3 = xe[3]*w[3];
                    float d4 = xe[4]*w[4], d5 = xe[5]*w[5], d6 = xe[6]*w[6], d7 = xe[7]*w[7];
                    float d8 = xe[8]*w[8];

                    acc[0] += d0 + C13 * (d1 + d2 + d3) + C15 * (d4 + d5 + d6 + d7 + d8);
                    #define T(a, b) (xe[a] * w[b] + xe[b] * w[a])
                    acc[1] += T(0,1) - C15 * T(1,6) - S35 * T(1,8) + S35 * T(2,5) + S35 * T(3,4);
                    acc[2] += T(0,2) + S35 * T(1,5) + C25 * T(2,6) + S35 * T(3,7);
                    acc[3] += T(0,3) + S35 * T(1,4) + S35 * T(2,7) - C15 * T(3,6) + S35 * T(3,8);
                    acc[4] += T(0,4) + IS3 * T(1,3) - C27 * T(4,6) + S37 * T(5,7);
                    acc[5] += T(0,5) + IS3 * T(1,2) + S37 * T(4,7) + C17 * T(5,6) - S37 * T(5,8);
                    acc[6] += T(0,6) - C13 * d1 + C23 * d2 - C13 * d3
                            - C27 * d4 + C17 * d5 + C27 * d6 + C17 * d7 - C27 * d8;
                    acc[7] += T(0,7) + IS3 * T(2,3) + S37 * T(4,5) + C17 * T(6,7) + S37 * T(7,8);
                    acc[8] += T(0,8) - IS3 * d1 + IS3 * d3 - S37 * d5 + S37 * d7 - C27 * T(6,8);
                    #undef T
                }
            }

            e0_c = e0_n; e0_n = e0_f;
            xa_c = xa_n; x8_c = x8_n;
            t = tn;
        }

        #pragma unroll
        for (int a = 0; a < NACC; ++a) acc[a] += __shfl_xor(acc[a], 32);

        if (half == 0) {
            if (MODE == 2) {
                m[(size_t)n * F + f] = acc[0];
            } else {
                float* mp = m + (size_t)n * KCH * F + f;
                #pragma unroll
                for (int a = 0; a < KCH; ++a) mp[a * F] = acc[a];
            }
        }
    }
}

// thread = (node, f). LDS tile for cross-feature mixing; per-lane weight columns.
__global__ __launch_bounds__(256) void node_full(float* __restrict__ x,
                                                 const float* __restrict__ m,
                                                 uint4* __restrict__ xhA,
                                                 ushort* __restrict__ xhB,
                                                 const float* __restrict__ w1,
                                                 const float* __restrict__ b1,
                                                 const float* __restrict__ w2,
                                                 const float* __restrict__ b2) {
    __shared__ float tile[8][KCH][F];
    int nl = threadIdx.x >> 5, f = threadIdx.x & 31;
    int n = blockIdx.x * 8 + nl;

    float w1c[F];
    #pragma unroll
    for (int fi = 0; fi < F; ++fi) w1c[fi] = w1[fi * F + f];

    float xk[KCH];
    #pragma unroll
    for (int k = 0; k < KCH; ++k) {
        xk[k] = x[((size_t)n * KCH + k) * F + f];
        tile[nl][k][f] = xk[k] + m[((size_t)n * KCH + k) * F + f];
    }
    __syncthreads();

    float o1[KCH];
    #pragma unroll
    for (int k = 0; k < KCH; ++k) {
        float s = 0.f;
        #pragma unroll
        for (int fi = 0; fi < F; ++fi) s = fmaf(tile[nl][k][fi], w1c[fi], s);
        o1[k] = s;
    }
    o1[0] += b1[f];
    float gate = 1.0f / (1.0f + expf(-o1[0]));
    __syncthreads();
    #pragma unroll
    for (int k = 0; k < KCH; ++k) tile[nl][k][f] = o1[k] * gate;
    __syncthreads();

    float w2c[F];
    #pragma unroll
    for (int fi = 0; fi < F; ++fi) w2c[fi] = w2[fi * F + f];

    float xn[KCH];
    #pragma unroll
    for (int k = 0; k < KCH; ++k) {
        float s = (k == 0) ? b2[f] : 0.f;
        #pragma unroll
        for (int fi = 0; fi < F; ++fi) s = fmaf(tile[nl][k][fi], w2c[fi], s);
        xn[k] = xk[k] + s;
        x[((size_t)n * KCH + k) * F + f] = xn[k];
    }

    uint4 ua;
    ua.x = pack2(xn[0], xn[1]); ua.y = pack2(xn[2], xn[3]);
    ua.z = pack2(xn[4], xn[5]); ua.w = pack2(xn[6], xn[7]);
    xhA[n * F + f] = ua;
    xhB[n * F + f] = __half_as_ushort(__float2half_rn(xn[8]));
}

__global__ __launch_bounds__(256) void node_last(const float* __restrict__ x,
                                                 const float* __restrict__ m1,
                                                 const float* __restrict__ w1,
                                                 const float* __restrict__ b1,
                                                 const float* __restrict__ w2,
                                                 const float* __restrict__ b2,
                                                 float* __restrict__ out) {
    __shared__ float tile[8][F];
    int nl = threadIdx.x >> 5, f = threadIdx.x & 31;
    int n = blockIdx.x * 8 + nl;

    float w1c[F];
    #pragma unroll
    for (int fi = 0; fi < F; ++fi) w1c[fi] = w1[fi * F + f];

    float x0 = x[(size_t)n * KCH * F + f];
    tile[nl][f] = x0 + m1[(size_t)n * F + f];
    __syncthreads();
    float s = 0.f;
    #pragma unroll
    for (int fi = 0; fi < F; ++fi) s = fmaf(tile[nl][fi], w1c[fi], s);
    s += b1[f];
    float gate = 1.0f / (1.0f + expf(-s));
    float h2 = s * gate;
    __syncthreads();
    tile[nl][f] = h2;
    __syncthreads();
    float w2c[F];
    #pragma unroll
    for (int fi = 0; fi < F; ++fi) w2c[fi] = w2[fi * F + f];
    float o = b2[f];
    #pragma unroll
    for (int fi = 0; fi < F; ++fi) o = fmaf(tile[nl][fi], w2c[fi], o);
    out[(size_t)n * F + f] = x0 + o;
}

extern "C" void kernel_launch(void* const* d_in, const int* in_sizes, int n_in,
                              void* d_out, int out_size, void* d_ws, size_t ws_size,
                              hipStream_t stream) {
    (void)in_sizes; (void)n_in; (void)out_size; (void)ws_size;
    const float* dr    = (const float*)d_in[0];
    const float* embed = (const float*)d_in[1];
    const float* rad_w = (const float*)d_in[2];
    const float* d1w   = (const float*)d_in[3];
    const float* d1b   = (const float*)d_in[4];
    const float* d2w   = (const float*)d_in[5];
    const float* d2b   = (const float*)d_in[6];
    const int*   Z     = (const int*)d_in[7];
    const int*   nidx  = (const int*)d_in[8];
    const int* idx_i = nidx;
    const int* idx_j = nidx + NE;

    // workspace layout (16B alignment maintained)
    float* x   = (float*)d_ws;                                  // NN*9*32 f32
    float* m   = x + (size_t)NN * KCH * F;                      // NN*9*32 f32
    uint4* xhA = (uint4*)(m + (size_t)NN * KCH * F);            // NN*32 uint4 (25.6MB)
    __half* x0h = (__half*)(xhA + (size_t)NN * F);              // NN*32 half (3.2MB)
    ushort* xhB = (ushort*)(x0h + (size_t)NN * F);              // NN*32 ushort (3.2MB)
    uint2* erec = (uint2*)(xhB + (size_t)NN * F);               // 3*NE uint2
    int* offs = (int*)(erec + (size_t)3 * NE);                  // NN+1
    int* head = offs + (NN + 1);                                // NN
    int* cnt  = head + NN;                                      // NN
    float* outp = (float*)d_out;

    hipMemsetAsync(cnt, 0, NN * sizeof(int), stream);
    hist_kernel<<<(NE + 255) / 256, 256, 0, stream>>>(idx_i, idx_j, dr, cnt);
    scan_kernel<<<1, SCAN_T, 0, stream>>>(cnt, offs, head);
    fill_kernel<<<(NE + 255) / 256, 256, 0, stream>>>(idx_i, idx_j, dr, head, erec);

    init_x<<<NN * F / 256, 256, 0, stream>>>(embed, Z, x, x0h);

    for (int i = 0; i < 3; ++i) {
        const float* rwi = rad_w + (size_t)i * 3 * 8 * F;
        const float* w1 = d1w + (size_t)i * F * F;
        const float* b1 = d1b + (size_t)i * F;
        const float* w2 = d2w + (size_t)i * F * F;
        const float* b2 = d2b + (size_t)i * F;
        if (i == 0) {
            gather_kernel<0><<<2048, 256, 0, stream>>>(erec, x0h, xhA, xhB, rwi, offs, m);
            node_full<<<NN / 8, 256, 0, stream>>>(x, m, xhA, xhB, w1, b1, w2, b2);
        } else if (i == 1) {
            gather_kernel<1><<<2048, 256, 0, stream>>>(erec, x0h, xhA, xhB, rwi, offs, m);
            node_full<<<NN / 8, 256, 0, stream>>>(x, m, xhA, xhB, w1, b1, w2, b2);
        } else {
            gather_kernel<2><<<2048, 256, 0, stream>>>(erec, x0h, xhA, xhB, rwi, offs, m);
            node_last<<<NN / 8, 256, 0, stream>>>(x, m, w1, b1, w2, b2, outp);
        }
    }
}

// Round 9
// 571.229 us; speedup vs baseline: 3.9484x; 1.0215x over previous
//
#include <hip/hip_runtime.h>
#include <hip/hip_fp16.h>
#include <math.h>

#define NN 50000
#define NE 640000
#define F  32
#define KCH 9
#define CUT 5.0f

#define C13 (1.0f/3.0f)
#define C23 (2.0f/3.0f)
#define C15 0.2f
#define C25 0.4f
#define C17 (1.0f/7.0f)
#define C27 (2.0f/7.0f)
#define IS3 0.5773502691896258f
#define S35 0.3464101615137755f
#define S37 0.2474358296526968f
#define S3  1.7320508075688772f

union U2H { unsigned int u; __half2 h; };

__device__ __forceinline__ unsigned int pack2(float a, float b) {
    U2H c; c.h = __floats2half2_rn(a, b); return c.u;
}
__device__ __forceinline__ float2 unpack2(unsigned int u) {
    U2H c; c.u = u; return __half22float2(c.h);
}
__device__ __forceinline__ float h2f(ushort u) {
    return __half2float(__ushort_as_half(u));
}

__global__ __launch_bounds__(256) void init_x(const float* __restrict__ embed,
                                              const int* __restrict__ Z,
                                              float* __restrict__ x0,
                                              ushort* __restrict__ x0h,
                                              uint4* __restrict__ xhA,
                                              ushort* __restrict__ xhB) {
    int idx = blockIdx.x * 256 + threadIdx.x;   // n*32 + f
    int n = idx >> 5, f = idx & 31;
    float v = embed[Z[n] * F + f];
    x0[idx] = v;
    unsigned int p = pack2(v, 0.f);
    x0h[idx] = (ushort)(p & 0xFFFFu);
    uint4 ua; ua.x = p; ua.y = 0u; ua.z = 0u; ua.w = 0u;
    xhA[idx] = ua;
    xhB[idx] = 0;
}

__global__ __launch_bounds__(256) void hist_kernel(const int* __restrict__ idx_i,
                                                   const int* __restrict__ idx_j,
                                                   const float* __restrict__ dr,
                                                   int* __restrict__ cnt) {
    int e = blockIdx.x * 256 + threadIdx.x;
    if (e >= NE) return;
    int ni = idx_i[e], nj = idx_j[e];
    float dx = dr[3 * e + 0], dy = dr[3 * e + 1], dz = dr[3 * e + 2];
    float r2 = fmaf(dx, dx, fmaf(dy, dy, dz * dz));
    if (ni != nj && r2 < CUT * CUT) atomicAdd(&cnt[ni], 1);
}

#define SCAN_T 1024
#define SCAN_C ((NN + SCAN_T - 1) / SCAN_T)

__global__ __launch_bounds__(SCAN_T) void scan_kernel(const int* __restrict__ cnt,
                                                      int* __restrict__ offs,
                                                      int* __restrict__ head) {
    __shared__ int ps[SCAN_T];
    int t = threadIdx.x;
    int b = t * SCAN_C;
    int e = min(b + SCAN_C, NN);
    int s = 0;
    for (int i = b; i < e; ++i) s += cnt[i];
    ps[t] = s;
    __syncthreads();
    for (int off = 1; off < SCAN_T; off <<= 1) {
        int v = (t >= off) ? ps[t - off] : 0;
        __syncthreads();
        ps[t] += v;
        __syncthreads();
    }
    int run = (t == 0) ? 0 : ps[t - 1];
    for (int i = b; i < e; ++i) { int c = cnt[i]; offs[i] = run; head[i] = run; run += c; }
    if (t == SCAN_T - 1) offs[NN] = ps[SCAN_T - 1];
}

// edge record 24 B: e0 = {u_xy, uz_half | nj<<16}, e1 = {rc01, rc23}, e2 = {rc45, rc67}
__global__ __launch_bounds__(256) void fill_kernel(const int* __restrict__ idx_i,
                                                   const int* __restrict__ idx_j,
                                                   const float* __restrict__ dr,
                                                   int* __restrict__ head,
                                                   uint2* __restrict__ erec) {
    int e = blockIdx.x * 256 + threadIdx.x;
    if (e >= NE) return;
    int ni = idx_i[e], nj = idx_j[e];
    float dx = dr[3 * e + 0], dy = dr[3 * e + 1], dz = dr[3 * e + 2];
    float r2 = fmaf(dx, dx, fmaf(dy, dy, dz * dz));
    if (!(ni != nj && r2 < CUT * CUT)) return;

    float r = sqrtf(r2);
    float inv = 1.0f / fmaxf(r, 1e-9f);
    float ux = dx * inv, uy = dy * inv, uz = dz * inv;

    float cut = expf(-r2 / fmaxf(CUT * CUT - r2, 1e-12f));
    float ur = r / (1.0f + r), vr = 1.0f - ur;
    float up2 = ur*ur, up3 = up2*ur, up4 = up3*ur, up5 = up4*ur, up6 = up5*ur, up7 = up6*ur;
    float vp2 = vr*vr, vp3 = vp2*vr, vp4 = vp3*vr, vp5 = vp4*vr, vp6 = vp5*vr, vp7 = vp6*vr;

    float rc0 = cut * vp7;
    float rc1 = cut * 7.f  * ur  * vp6;
    float rc2 = cut * 21.f * up2 * vp5;
    float rc3 = cut * 35.f * up3 * vp4;
    float rc4 = cut * 35.f * up4 * vp3;
    float rc5 = cut * 21.f * up5 * vp2;
    float rc6 = cut * 7.f  * up6 * vr;
    float rc7 = cut * up7;

    int p = atomicAdd(&head[ni], 1);
    uint2 e0, e1, e2;
    U2H zh; zh.h = __floats2half2_rn(uz, 0.f);
    e0.x = pack2(ux, uy);
    e0.y = (zh.u & 0xFFFFu) | ((unsigned int)nj << 16);
    e1.x = pack2(rc0, rc1); e1.y = pack2(rc2, rc3);
    e2.x = pack2(rc4, rc5); e2.y = pack2(rc6, rc7);
    erec[(size_t)3 * p + 0] = e0;
    erec[(size_t)3 * p + 1] = e1;
    erec[(size_t)3 * p + 2] = e2;
}

// MODE: 0 = FIRST (x only row0 nonzero, reads x0h), 1 = MID (full Gaunt), 2 = LAST (y0 only)
// Pipeline: JIT consumables (e1,e2) issued FIRST each iteration; depth-2 prefetch on the
// random xe loads issued LAST (vmcnt retires in order -> older consumables don't wait on
// younger prefetches). e0 stream runs depth-3 to supply nj two edges ahead.
template<int MODE>
__global__ __launch_bounds__(256) void gather_kernel(const uint2* __restrict__ erec,
                                                     const ushort* __restrict__ x0h,
                                                     const uint4* __restrict__ xhA,
                                                     const ushort* __restrict__ xhB,
                                                     const float* __restrict__ rw_iter,
                                                     const int* __restrict__ offs,
                                                     float* __restrict__ m) {
    const int NWAVES = 2048 * 4;
    int lane = threadIdx.x & 63;
    int wid  = threadIdx.x >> 6;
    int half = lane >> 5;
    int f    = lane & 31;
    int gw   = blockIdx.x * 4 + wid;

    float rwv[24];
    #pragma unroll
    for (int lb = 0; lb < 24; ++lb) rwv[lb] = rw_iter[lb * F + f];
    if (MODE == 2) {
        #pragma unroll
        for (int lb = 8; lb < 16; ++lb) rwv[lb] *= C13;
        #pragma unroll
        for (int lb = 16; lb < 24; ++lb) rwv[lb] *= C15;
    }

    constexpr int NACC = (MODE == 2) ? 1 : KCH;

    for (int n = gw; n < NN; n += NWAVES) {
        int start = offs[n], end = offs[n + 1];

        float acc[NACC];
        #pragma unroll
        for (int a = 0; a < NACC; ++a) acc[a] = 0.f;

        int t = start + half;
        uint2 e0_0 = {}, e0_1 = {}, e0_2 = {};
        uint4 xa_0 = {}, xa_1 = {};
        ushort x8_0 = 0, x8_1 = 0;

        if (t < end) {
            int c1 = min(t + 2, end - 1);
            int c2 = min(t + 4, end - 1);
            e0_0 = erec[(size_t)3 * t];
            e0_1 = erec[(size_t)3 * c1];
            e0_2 = erec[(size_t)3 * c2];
            int nj0 = (int)(e0_0.y >> 16);
            int nj1 = (int)(e0_1.y >> 16);
            if (MODE == 0) {
                x8_0 = x0h[nj0 * F + f];
                x8_1 = x0h[nj1 * F + f];
            } else {
                xa_0 = xhA[nj0 * F + f]; x8_0 = xhB[nj0 * F + f];
                xa_1 = xhA[nj1 * F + f]; x8_1 = xhB[nj1 * F + f];
            }
        }

        while (t < end) {
            // ---- JIT consumables first (retire before younger prefetches) ----
            uint2 e1 = erec[(size_t)3 * t + 1];
            uint2 e2 = erec[(size_t)3 * t + 2];

            // ---- prefetches last ----
            int c3 = min(t + 6, end - 1);
            uint2 e0_3 = erec[(size_t)3 * c3];
            int nj2 = (int)(e0_2.y >> 16);
            uint4 xa_2 = {};
            ushort x8_2;
            if (MODE == 0) {
                x8_2 = x0h[nj2 * F + f];
            } else {
                xa_2 = xhA[nj2 * F + f];
                x8_2 = xhB[nj2 * F + f];
            }

            // ---- compute edge t from *_0 state + e1/e2 ----
            float2 uxy = unpack2(e0_0.x);
            float ux = uxy.x, uy = uxy.y;
            float uz = unpack2(e0_0.y).x;     // low half; high half is nj
            float2 rcA = unpack2(e1.x);
            float2 rcB = unpack2(e1.y);
            float2 rcC = unpack2(e2.x);
            float2 rcD = unpack2(e2.y);

            float g0, g1, g2;
            g0 = rcA.x * rwv[0];
            g0 = fmaf(rcA.y, rwv[1], g0); g0 = fmaf(rcB.x, rwv[2], g0); g0 = fmaf(rcB.y, rwv[3], g0);
            g0 = fmaf(rcC.x, rwv[4], g0); g0 = fmaf(rcC.y, rwv[5], g0); g0 = fmaf(rcD.x, rwv[6], g0);
            g0 = fmaf(rcD.y, rwv[7], g0);
            g1 = rcA.x * rwv[8];
            g1 = fmaf(rcA.y, rwv[9],  g1); g1 = fmaf(rcB.x, rwv[10], g1); g1 = fmaf(rcB.y, rwv[11], g1);
            g1 = fmaf(rcC.x, rwv[12], g1); g1 = fmaf(rcC.y, rwv[13], g1); g1 = fmaf(rcD.x, rwv[14], g1);
            g1 = fmaf(rcD.y, rwv[15], g1);
            g2 = rcA.x * rwv[16];
            g2 = fmaf(rcA.y, rwv[17], g2); g2 = fmaf(rcB.x, rwv[18], g2); g2 = fmaf(rcB.y, rwv[19], g2);
            g2 = fmaf(rcC.x, rwv[20], g2); g2 = fmaf(rcC.y, rwv[21], g2); g2 = fmaf(rcD.x, rwv[22], g2);
            g2 = fmaf(rcD.y, rwv[23], g2);

            if (MODE == 0) {
                float xe0 = h2f(x8_0);
                float s2 = S3 * g2;
                acc[0] = fmaf(xe0, g0, acc[0]);
                acc[1] = fmaf(xe0, uy * g1, acc[1]);
                acc[2] = fmaf(xe0, uz * g1, acc[2]);
                acc[3] = fmaf(xe0, ux * g1, acc[3]);
                acc[4] = fmaf(xe0, s2 * ux * uy, acc[4]);
                acc[5] = fmaf(xe0, s2 * uy * uz, acc[5]);
                acc[6] = fmaf(xe0, fmaf(1.5f * uz, uz, -0.5f) * g2, acc[6]);
                acc[7] = fmaf(xe0, s2 * ux * uz, acc[7]);
                acc[8] = fmaf(xe0, 0.5f * s2 * (ux * ux - uy * uy), acc[8]);
            } else {
                float xe[9];
                {
                    float2 p;
                    p = unpack2(xa_0.x); xe[0] = p.x; xe[1] = p.y;
                    p = unpack2(xa_0.y); xe[2] = p.x; xe[3] = p.y;
                    p = unpack2(xa_0.z); xe[4] = p.x; xe[5] = p.y;
                    p = unpack2(xa_0.w); xe[6] = p.x; xe[7] = p.y;
                    xe[8] = h2f(x8_0);
                }
                if (MODE == 2) {
                    float dot1 = uy * xe[1];
                    dot1 = fmaf(uz, xe[2], dot1);
                    dot1 = fmaf(ux, xe[3], dot1);
                    float Y4 = S3 * ux * uy, Y5 = S3 * uy * uz, Y7 = S3 * ux * uz;
                    float Y6 = fmaf(1.5f * uz, uz, -0.5f);
                    float Y8 = 0.5f * S3 * (ux * ux - uy * uy);
                    float dot2 = Y4 * xe[4];
                    dot2 = fmaf(Y5, xe[5], dot2);
                    dot2 = fmaf(Y6, xe[6], dot2);
                    dot2 = fmaf(Y7, xe[7], dot2);
                    dot2 = fmaf(Y8, xe[8], dot2);
                    acc[0] = fmaf(g0, xe[0], acc[0]);
                    acc[0] = fmaf(g1, dot1, acc[0]);
                    acc[0] = fmaf(g2, dot2, acc[0]);
                } else {
                    float s2 = S3 * g2;
                    float w[9];
                    w[0] = g0;
                    w[1] = uy * g1; w[2] = uz * g1; w[3] = ux * g1;
                    w[4] = s2 * ux * uy;
                    w[5] = s2 * uy * uz;
                    w[6] = fmaf(1.5f * uz, uz, -0.5f) * g2;
                    w[7] = s2 * ux * uz;
                    w[8] = 0.5f * s2 * (ux * ux - uy * uy);

                    float d0 = xe[0]*w[0], d1 = xe[1]*w[1], d2 = xe[2]*w[2], d3 = xe[3]*w[3];
                    float d4 = xe[4]*w[4], d5 = xe[5]*w[5], d6 = xe[6]*w[6], d7 = xe[7]*w[7];
                    float d8 = xe[8]*w[8];

                    acc[0] += d0 + C13 * (d1 + d2 + d3) + C15 * (d4 + d5 + d6 + d7 + d8);
                    #define T(a, b) (xe[a] * w[b] + xe[b] * w[a])
                    acc[1] += T(0,1) - C15 * T(1,6) - S35 * T(1,8) + S35 * T(2,5) + S35 * T(3,4);
                    acc[2] += T(0,2) + S35 * T(1,5) + C25 * T(2,6) + S35 * T(3,7);
                    acc[3] += T(0,3) + S35 * T(1,4) + S35 * T(2,7) - C15 * T(3,6) + S35 * T(3,8);
                    acc[4] += T(0,4) + IS3 * T(1,3) - C27 * T(4,6) + S37 * T(5,7);
                    acc[5] += T(0,5) + IS3 * T(1,2) + S37 * T(4,7) + C17 * T(5,6) - S37 * T(5,8);
                    acc[6] += T(0,6) - C13 * d1 + C23 * d2 - C13 * d3
                            - C27 * d4 + C17 * d5 + C27 * d6 + C17 * d7 - C27 * d8;
                    acc[7] += T(0,7) + IS3 * T(2,3) + S37 * T(4,5) + C17 * T(6,7) + S37 * T(7,8);
                    acc[8] += T(0,8) - IS3 * d1 + IS3 * d3 - S37 * d5 + S37 * d7 - C27 * T(6,8);
                    #undef T
                }
            }

            // rotate pipeline
            e0_0 = e0_1; e0_1 = e0_2; e0_2 = e0_3;
            xa_0 = xa_1; xa_1 = xa_2;
            x8_0 = x8_1; x8_1 = x8_2;
            t += 2;
        }

        #pragma unroll
        for (int a = 0; a < NACC; ++a) acc[a] += __shfl_xor(acc[a], 32);

        if (half == 0) {
            if (MODE == 2) {
                m[(size_t)n * F + f] = acc[0];
            } else {
                float* mp = m + (size_t)n * KCH * F + f;
                #pragma unroll
                for (int a = 0; a < KCH; ++a) mp[a * F] = acc[a];
            }
        }
    }
}

// thread = (node, f). State lives in fp16 (xhA/xhB) + f32 master of k=0 row (x0).
__global__ __launch_bounds__(256) void node_full(float* __restrict__ x0,
                                                 const float* __restrict__ m,
                                                 uint4* __restrict__ xhA,
                                                 ushort* __restrict__ xhB,
                                                 const float* __restrict__ w1,
                                                 const float* __restrict__ b1,
                                                 const float* __restrict__ w2,
                                                 const float* __restrict__ b2) {
    __shared__ float tile[8][KCH][F];
    int nl = threadIdx.x >> 5, f = threadIdx.x & 31;
    int n = blockIdx.x * 8 + nl;

    float w1c[F];
    #pragma unroll
    for (int fi = 0; fi < F; ++fi) w1c[fi] = w1[fi * F + f];

    float xk[KCH];
    {
        uint4 ua = xhA[n * F + f];
        ushort ub = xhB[n * F + f];
        float2 p;
        p = unpack2(ua.x); xk[0] = p.x; xk[1] = p.y;
        p = unpack2(ua.y); xk[2] = p.x; xk[3] = p.y;
        p = unpack2(ua.z); xk[4] = p.x; xk[5] = p.y;
        p = unpack2(ua.w); xk[6] = p.x; xk[7] = p.y;
        xk[8] = h2f(ub);
    }
    xk[0] = x0[n * F + f];   // f32 master for the residual-critical row

    #pragma unroll
    for (int k = 0; k < KCH; ++k)
        tile[nl][k][f] = xk[k] + m[((size_t)n * KCH + k) * F + f];
    __syncthreads();

    float o1[KCH];
    #pragma unroll
    for (int k = 0; k < KCH; ++k) {
        float s = 0.f;
        #pragma unroll
        for (int fi = 0; fi < F; ++fi) s = fmaf(tile[nl][k][fi], w1c[fi], s);
        o1[k] = s;
    }
    o1[0] += b1[f];
    float gate = 1.0f / (1.0f + expf(-o1[0]));
    __syncthreads();
    #pragma unroll
    for (int k = 0; k < KCH; ++k) tile[nl][k][f] = o1[k] * gate;
    __syncthreads();

    float w2c[F];
    #pragma unroll
    for (int fi = 0; fi < F; ++fi) w2c[fi] = w2[fi * F + f];

    float xn[KCH];
    #pragma unroll
    for (int k = 0; k < KCH; ++k) {
        float s = (k == 0) ? b2[f] : 0.f;
        #pragma unroll
        for (int fi = 0; fi < F; ++fi) s = fmaf(tile[nl][k][fi], w2c[fi], s);
        xn[k] = xk[k] + s;
    }

    x0[n * F + f] = xn[0];
    uint4 ua;
    ua.x = pack2(xn[0], xn[1]); ua.y = pack2(xn[2], xn[3]);
    ua.z = pack2(xn[4], xn[5]); ua.w = pack2(xn[6], xn[7]);
    xhA[n * F + f] = ua;
    xhB[n * F + f] = __half_as_ushort(__float2half_rn(xn[8]));
}

__global__ __launch_bounds__(256) void node_last(const float* __restrict__ x0,
                                                 const float* __restrict__ m1,
                                                 const float* __restrict__ w1,
                                                 const float* __restrict__ b1,
                                                 const float* __restrict__ w2,
                                                 const float* __restrict__ b2,
                                                 float* __restrict__ out) {
    __shared__ float tile[8][F];
    int nl = threadIdx.x >> 5, f = threadIdx.x & 31;
    int n = blockIdx.x * 8 + nl;

    float w1c[F];
    #pragma unroll
    for (int fi = 0; fi < F; ++fi) w1c[fi] = w1[fi * F + f];

    float xv = x0[n * F + f];
    tile[nl][f] = xv + m1[(size_t)n * F + f];
    __syncthreads();
    float s = 0.f;
    #pragma unroll
    for (int fi = 0; fi < F; ++fi) s = fmaf(tile[nl][fi], w1c[fi], s);
    s += b1[f];
    float gate = 1.0f / (1.0f + expf(-s));
    float h2 = s * gate;
    __syncthreads();
    tile[nl][f] = h2;
    __syncthreads();
    float w2c[F];
    #pragma unroll
    for (int fi = 0; fi < F; ++fi) w2c[fi] = w2[fi * F + f];
    float o = b2[f];
    #pragma unroll
    for (int fi = 0; fi < F; ++fi) o = fmaf(tile[nl][fi], w2c[fi], o);
    out[(size_t)n * F + f] = xv + o;
}

extern "C" void kernel_launch(void* const* d_in, const int* in_sizes, int n_in,
                              void* d_out, int out_size, void* d_ws, size_t ws_size,
                              hipStream_t stream) {
    (void)in_sizes; (void)n_in; (void)out_size; (void)ws_size;
    const float* dr    = (const float*)d_in[0];
    const float* embed = (const float*)d_in[1];
    const float* rad_w = (const float*)d_in[2];
    const float* d1w   = (const float*)d_in[3];
    const float* d1b   = (const float*)d_in[4];
    const float* d2w   = (const float*)d_in[5];
    const float* d2b   = (const float*)d_in[6];
    const int*   Z     = (const int*)d_in[7];
    const int*   nidx  = (const int*)d_in[8];
    const int* idx_i = nidx;
    const int* idx_j = nidx + NE;

    // workspace layout (16B-aligned head)
    uint4* xhA = (uint4*)d_ws;                                  // NN*F uint4 (25.6MB)
    float* m   = (float*)(xhA + (size_t)NN * F);                // NN*9*F f32 (57.6MB)
    float* x0  = m + (size_t)NN * KCH * F;                      // NN*F f32 (6.4MB)
    ushort* x0h = (ushort*)(x0 + (size_t)NN * F);               // NN*F u16 (3.2MB)
    ushort* xhB = x0h + (size_t)NN * F;                         // NN*F u16 (3.2MB)
    uint2* erec = (uint2*)(xhB + (size_t)NN * F);               // 3*NE uint2 (15.4MB)
    int* offs = (int*)(erec + (size_t)3 * NE);                  // NN+1
    int* head = offs + (NN + 1);                                // NN
    int* cnt  = head + NN;                                      // NN
    float* outp = (float*)d_out;

    hipMemsetAsync(cnt, 0, NN * sizeof(int), stream);
    hist_kernel<<<(NE + 255) / 256, 256, 0, stream>>>(idx_i, idx_j, dr, cnt);
    scan_kernel<<<1, SCAN_T, 0, stream>>>(cnt, offs, head);
    fill_kernel<<<(NE + 255) / 256, 256, 0, stream>>>(idx_i, idx_j, dr, head, erec);

    init_x<<<NN * F / 256, 256, 0, stream>>>(embed, Z, x0, x0h, xhA, xhB);

    for (int i = 0; i < 3; ++i) {
        const float* rwi = rad_w + (size_t)i * 3 * 8 * F;
        const float* w1 = d1w + (size_t)i * F * F;
        const float* b1 = d1b + (size_t)i * F;
        const float* w2 = d2w + (size_t)i * F * F;
        const float* b2 = d2b + (size_t)i * F;
        if (i == 0) {
            gather_kernel<0><<<2048, 256, 0, stream>>>(erec, x0h, xhA, xhB, rwi, offs, m);
            node_full<<<NN / 8, 256, 0, stream>>>(x0, m, xhA, xhB, w1, b1, w2, b2);
        } else if (i == 1) {
            gather_kernel<1><<<2048, 256, 0, stream>>>(erec, x0h, xhA, xhB, rwi, offs, m);
            node_full<<<NN / 8, 256, 0, stream>>>(x0, m, xhA, xhB, w1, b1, w2, b2);
        } else {
            gather_kernel<2><<<2048, 256, 0, stream>>>(erec, x0h, xhA, xhB, rwi, offs, m);
            node_last<<<NN / 8, 256, 0, stream>>>(x0, m, w1, b1, w2, b2, outp);
        }
    }
}